// Round 19
// baseline (123.784 us; speedup 1.0000x reference)
//
#include <hip/hip_runtime.h>

#define BB 4
#define SS 1024
#define DD 1024
#define HH 16
#define DKK 64
#define MM (BB*SS)   // 4096

typedef __bf16 bf16;
typedef __bf16 bf16x8 __attribute__((ext_vector_type(8)));
typedef float f32x4 __attribute__((ext_vector_type(4)));
typedef float f32x16 __attribute__((ext_vector_type(16)));

__device__ __forceinline__ f32x4 mfma16(bf16x8 a, bf16x8 b, f32x4 c) {
  return __builtin_amdgcn_mfma_f32_16x16x32_bf16(a, b, c, 0, 0, 0);
}
__device__ __forceinline__ f32x16 mfma32(bf16x8 a, bf16x8 b, f32x16 c) {
  return __builtin_amdgcn_mfma_f32_32x32x16_bf16(a, b, c, 0, 0, 0);
}
__device__ __forceinline__ float fexp2(float x) {
  return __builtin_amdgcn_exp2f(x);
}
__device__ __forceinline__ void gld_lds16(const bf16* g, bf16* l) {
  __builtin_amdgcn_global_load_lds(
      (const __attribute__((address_space(1))) void*)g,
      (__attribute__((address_space(3))) void*)l, 16, 0, 0);
}

// ------- prep: fp32->bf16 convert (7 tensors) + mask bits, one dispatch ----
__global__ __launch_bounds__(256)
void k_prep(const float* __restrict__ s0, const float* __restrict__ s1,
            const float* __restrict__ s2, const float* __restrict__ s3,
            const float* __restrict__ s4, const float* __restrict__ s5,
            const float* __restrict__ s6,
            bf16* __restrict__ d0, bf16* __restrict__ d1, bf16* __restrict__ d2,
            bf16* __restrict__ d3, bf16* __restrict__ d4, bf16* __restrict__ d5,
            bf16* __restrict__ d6,
            const int* __restrict__ mask, unsigned* __restrict__ bits) {
  const int t = blockIdx.y;
  if (t < 7) {
    const float* s = (t == 0) ? s0 : (t == 1) ? s1 : (t == 2) ? s2
                   : (t == 3) ? s3 : (t == 4) ? s4 : (t == 5) ? s5 : s6;
    bf16* d = (t == 0) ? d0 : (t == 1) ? d1 : (t == 2) ? d2
            : (t == 3) ? d3 : (t == 4) ? d4 : (t == 5) ? d5 : d6;
    const int n = (t < 3) ? (MM * DD) : (DD * DD);
    const int i0 = (blockIdx.x * 256 + threadIdx.x) * 8;
    if (i0 >= n) return;
    const f32x4 a = *(const f32x4*)(s + i0);
    const f32x4 bvv = *(const f32x4*)(s + i0 + 4);
    bf16x8 o;
#pragma unroll
    for (int j = 0; j < 4; ++j) { o[j] = (bf16)a[j]; o[4 + j] = (bf16)bvv[j]; }
    *(bf16x8*)(d + i0) = o;
    return;
  }
  const int tid = threadIdx.x;
  const int lane = tid & 63, wv = tid >> 6;
#pragma unroll
  for (int rr = 0; rr < 2; ++rr) {
    const int row = blockIdx.x * 2 + rr;           // b*S + q
    const int b = row >> 10, q = row & 1023;
    const int qblk = q >> 6, qt = (q >> 5) & 1, l = q & 31;
    const size_t base = ((size_t)(b * 16 + qblk) * 2 + qt) * 4;
#pragma unroll
    for (int it = 0; it < 4; ++it) {
      const int cb = it * 256 + wv * 64;
      unsigned long long bal = __ballot(mask[(size_t)row * SS + cb + lane] != 0);
      if (lane == 0) {
        const int c0 = cb >> 5;
#pragma unroll
        for (int dd = 0; dd < 2; ++dd) {
          const int c = c0 + dd;
          bits[((base + (c >> 3)) * 8 + (c & 7)) * 32 + l] =
              (unsigned)(bal >> (32 * dd));
        }
      }
    }
  }
}

// ---------------- mask -> bitmask (standalone, fallback path) --------------
__global__ __launch_bounds__(256) void k_mask_bits(const int* __restrict__ mask,
                                                   unsigned* __restrict__ bits) {
  const int row = blockIdx.x;
  const int b = row >> 10, q = row & 1023;
  const int qblk = q >> 6, qt = (q >> 5) & 1, l = q & 31;
  const size_t base = ((size_t)(b * 16 + qblk) * 2 + qt) * 4;
  const int tid = threadIdx.x;
  const int lane = tid & 63, wv = tid >> 6;
#pragma unroll
  for (int it = 0; it < 4; ++it) {
    const int cb = it * 256 + wv * 64;
    unsigned long long bal = __ballot(mask[(size_t)row * SS + cb + lane] != 0);
    if (lane == 0) {
      const int c0 = cb >> 5;
#pragma unroll
      for (int dd = 0; dd < 2; ++dd) {
        const int c = c0 + dd;
        bits[((base + (c >> 3)) * 8 + (c & 7)) * 32 + l] =
            (unsigned)(bal >> (32 * dd));
      }
    }
  }
}

// ------- K/V -> MFMA fragment order (r11-verified layout) ------------------
// Kf tile[kvb]: elem kt*512 + lane*8 + j = K[kv0+l31][kt*16+hi*8+j]
// Vf tile[kvb]: elem (s2*2+dt)*512 + lane*8 + j = V[kv0+s2*16+hi*8+j][dt*32+l31]
__global__ __launch_bounds__(256)
void k_frag(const bf16* __restrict__ K, const bf16* __restrict__ V,
            bf16* __restrict__ Kf, bf16* __restrict__ Vf) {
  __shared__ bf16 Kl[32 * 66];
  __shared__ bf16 Vl[32 * 66];
  const int kvb = blockIdx.x, h = blockIdx.y, b = blockIdx.z;
  const int tid = threadIdx.x;
  const int r = tid >> 3, c0 = (tid & 7) * 8;
  const size_t src = (size_t)(b * SS + kvb * 32 + r) * DD + h * 64 + c0;
  *(bf16x8*)&Kl[r * 66 + c0] = *(const bf16x8*)(K + src);
  *(bf16x8*)&Vl[r * 66 + c0] = *(const bf16x8*)(V + src);
  __syncthreads();
  const int lane = tid & 63, l31 = lane & 31, hi = lane >> 5;
  const size_t tb = ((size_t)((b * HH + h) * 32 + kvb)) * 2048 + tid * 8;
  {
    const int kt = tid >> 6;
    bf16x8 ok;
#pragma unroll
    for (int j = 0; j < 8; ++j) ok[j] = Kl[l31 * 66 + kt * 16 + hi * 8 + j];
    *(bf16x8*)(Kf + tb) = ok;
  }
  {
    const int s2 = tid >> 7, dt = (tid >> 6) & 1;
    bf16x8 ov;
#pragma unroll
    for (int j = 0; j < 8; ++j)
      ov[j] = Vl[(s2 * 16 + hi * 8 + j) * 66 + dt * 32 + l31];
    *(bf16x8*)(Vf + tb) = ov;
  }
}

// Q pre-scaled by 1/sqrt(dk) * log2(e): attention runs in exp2 domain.
#define QSCALE 0.1803368801111204f

// ---------------- legacy GEMM (fallback when ws too small) ----------------
template<int AF32, int CF32>
__device__ __forceinline__ void gemm_body(const void* __restrict__ Ap,
                                          const float* __restrict__ Wp,
                                          void* __restrict__ Cp,
                                          int Mtot, int N, int K, int blk,
                                          float oscale) {
  __shared__ bf16 Al[128 * 40];
  __shared__ bf16 Bl[128 * 40];
  const int tid = threadIdx.x;
  const int lane = tid & 63;
  const int l15 = lane & 15, l4 = lane >> 4;
  const int wv = tid >> 6;
  const int nbm = Mtot >> 7;
  const int bm = blk % nbm, bn = blk / nbm;
  const size_t m0 = (size_t)bm << 7, n0 = (size_t)bn << 7;
  const int wr = (wv >> 1) << 6, wc = (wv & 1) << 6;
  const int srow = tid >> 2, scol = (tid & 3) << 3;

  f32x4 acc[4][4];
#pragma unroll
  for (int i = 0; i < 4; ++i)
#pragma unroll
    for (int j = 0; j < 4; ++j) acc[i][j] = f32x4{0.f, 0.f, 0.f, 0.f};

  for (int k0 = 0; k0 < K; k0 += 32) {
#pragma unroll
    for (int c = 0; c < 2; ++c) {
      const int row = (c << 6) + srow;
      bf16x8 av;
      if (AF32) {
        const float* s = (const float*)Ap + (m0 + row) * (size_t)K + k0 + scol;
        f32x4 v0 = *(const f32x4*)s;
        f32x4 v1 = *(const f32x4*)(s + 4);
#pragma unroll
        for (int j = 0; j < 4; ++j) { av[j] = (bf16)v0[j]; av[4 + j] = (bf16)v1[j]; }
      } else {
        av = *(const bf16x8*)((const bf16*)Ap + (m0 + row) * (size_t)K + k0 + scol);
      }
      *(bf16x8*)&Al[row * 40 + scol] = av;

      const float* ws_ = Wp + (n0 + row) * (size_t)K + k0 + scol;
      f32x4 w0 = *(const f32x4*)ws_;
      f32x4 w1 = *(const f32x4*)(ws_ + 4);
      bf16x8 wv8;
#pragma unroll
      for (int j = 0; j < 4; ++j) { wv8[j] = (bf16)w0[j]; wv8[4 + j] = (bf16)w1[j]; }
      *(bf16x8*)&Bl[row * 40 + scol] = wv8;
    }
    __syncthreads();

    bf16x8 af[4], bfv[4];
#pragma unroll
    for (int t = 0; t < 4; ++t) {
      af[t]  = *(const bf16x8*)&Al[(wr + t * 16 + l15) * 40 + l4 * 8];
      bfv[t] = *(const bf16x8*)&Bl[(wc + t * 16 + l15) * 40 + l4 * 8];
    }
    __builtin_amdgcn_s_setprio(1);
#pragma unroll
    for (int mt = 0; mt < 4; ++mt)
#pragma unroll
      for (int nt = 0; nt < 4; ++nt)
        acc[mt][nt] = mfma16(af[mt], bfv[nt], acc[mt][nt]);
    __builtin_amdgcn_s_setprio(0);
    __syncthreads();
  }

#pragma unroll
  for (int mt = 0; mt < 4; ++mt)
#pragma unroll
    for (int nt = 0; nt < 4; ++nt)
#pragma unroll
      for (int r = 0; r < 4; ++r) {
        const size_t row = m0 + wr + mt * 16 + l4 * 4 + r;
        const size_t col = n0 + wc + nt * 16 + l15;
        if (CF32) ((float*)Cp)[row * N + col] = acc[mt][nt][r];
        else      ((bf16*)Cp)[row * N + col] = (bf16)(acc[mt][nt][r] * oscale);
      }
}

__global__ __launch_bounds__(256)
void k_gemm_qkv(const float* __restrict__ A0, const float* __restrict__ A1,
                const float* __restrict__ A2, const float* __restrict__ W0,
                const float* __restrict__ W1, const float* __restrict__ W2,
                bf16* __restrict__ C0, bf16* __restrict__ C1, bf16* __restrict__ C2) {
  const int z = blockIdx.z;
  const float* A = (z == 0) ? A0 : (z == 1) ? A1 : A2;
  const float* W = (z == 0) ? W0 : (z == 1) ? W1 : W2;
  bf16* C = (z == 0) ? C0 : (z == 1) ? C1 : C2;
  const float sc = (z == 0) ? QSCALE : 1.0f;
  gemm_body<1, 0>(A, W, C, MM, DD, DD, blockIdx.x, sc);
}

__global__ __launch_bounds__(256)
void k_gemm_out(const bf16* __restrict__ A, const float* __restrict__ W,
                float* __restrict__ C) {
  gemm_body<0, 1>(A, W, C, MM, DD, DD, blockIdx.x, 1.0f);
}

// ---------------- bf16 GEMM with global_load_lds (m97 structure) ----------
// All outputs row-major (coalesced bf16x8 stores; fragment permute is done
// by the separate k_frag kernel — the z==1 direct scatter cost ~10us in RMW).
__global__ __launch_bounds__(256)
void k_gemm_qkv_b16(const bf16* __restrict__ A0, const bf16* __restrict__ A1,
                    const bf16* __restrict__ A2, const bf16* __restrict__ W0,
                    const bf16* __restrict__ W1, const bf16* __restrict__ W2,
                    bf16* __restrict__ C0, bf16* __restrict__ C1,
                    bf16* __restrict__ C2) {
  __shared__ bf16 Al[128 * 32];
  __shared__ bf16 Bl[128 * 32];
  const int z = blockIdx.z;
  const bf16* A = (z == 0) ? A0 : (z == 1) ? A1 : A2;
  const bf16* W = (z == 0) ? W0 : (z == 1) ? W1 : W2;
  bf16* C = (z == 0) ? C0 : (z == 1) ? C1 : C2;
  const float oscale = (z == 0) ? QSCALE : 1.0f;

  const int tid = threadIdx.x, lane = tid & 63, w = tid >> 6;
  const int l15 = lane & 15, l4 = lane >> 4;
  const int bm = blockIdx.x & 31, bn = blockIdx.x >> 5;
  const size_t m0 = (size_t)bm << 7, n0 = (size_t)bn << 7;
  const int wr = (w >> 1) << 6, wc = (w & 1) << 6;
  const int srow = w * 32 + (lane >> 2);
  const int scol = (lane & 3) << 3;

  f32x4 acc[4][4];
#pragma unroll
  for (int i = 0; i < 4; ++i)
#pragma unroll
    for (int j = 0; j < 4; ++j) acc[i][j] = f32x4{0.f, 0.f, 0.f, 0.f};

  for (int k0 = 0; k0 < DD; k0 += 32) {
    const bf16* ga = A + (m0 + srow) * (size_t)DD + k0 + scol;
    const bf16* gb = W + (n0 + srow) * (size_t)DD + k0 + scol;
    gld_lds16(ga,            &Al[(w * 32) * 32]);
    gld_lds16(ga + 16 * DD,  &Al[(w * 32 + 16) * 32]);
    gld_lds16(gb,            &Bl[(w * 32) * 32]);
    gld_lds16(gb + 16 * DD,  &Bl[(w * 32 + 16) * 32]);
    __syncthreads();

    bf16x8 af[4], bfv[4];
#pragma unroll
    for (int t = 0; t < 4; ++t) {
      af[t]  = *(const bf16x8*)&Al[(wr + t * 16 + l15) * 32 + l4 * 8];
      bfv[t] = *(const bf16x8*)&Bl[(wc + t * 16 + l15) * 32 + l4 * 8];
    }
#pragma unroll
    for (int mt = 0; mt < 4; ++mt)
#pragma unroll
      for (int nt = 0; nt < 4; ++nt)
        acc[mt][nt] = mfma16(af[mt], bfv[nt], acc[mt][nt]);
    __syncthreads();
  }

#pragma unroll
  for (int mt = 0; mt < 4; ++mt)
#pragma unroll
    for (int nt = 0; nt < 4; ++nt)
#pragma unroll
      for (int r = 0; r < 4; ++r) {
        const size_t row = m0 + wr + mt * 16 + l4 * 4 + r;
        const size_t col = n0 + wc + nt * 16 + l15;
        C[row * DD + col] = (bf16)(acc[mt][nt][r] * oscale);
      }
}

__global__ __launch_bounds__(256)
void k_gemm_out_b16(const bf16* __restrict__ A, const bf16* __restrict__ W,
                    float* __restrict__ C) {
  __shared__ bf16 Al[128 * 32];
  __shared__ bf16 Bl[128 * 32];
  const int tid = threadIdx.x, lane = tid & 63, w = tid >> 6;
  const int l15 = lane & 15, l4 = lane >> 4;
  const int bm = blockIdx.x & 31, bn = blockIdx.x >> 5;
  const size_t m0 = (size_t)bm << 7, n0 = (size_t)bn << 7;
  const int wr = (w >> 1) << 6, wc = (w & 1) << 6;
  const int srow = w * 32 + (lane >> 2);
  const int scol = (lane & 3) << 3;

  f32x4 acc[4][4];
#pragma unroll
  for (int i = 0; i < 4; ++i)
#pragma unroll
    for (int j = 0; j < 4; ++j) acc[i][j] = f32x4{0.f, 0.f, 0.f, 0.f};

  for (int k0 = 0; k0 < DD; k0 += 32) {
    const bf16* ga = A + (m0 + srow) * (size_t)DD + k0 + scol;
    const bf16* gb = W + (n0 + srow) * (size_t)DD + k0 + scol;
    gld_lds16(ga,            &Al[(w * 32) * 32]);
    gld_lds16(ga + 16 * DD,  &Al[(w * 32 + 16) * 32]);
    gld_lds16(gb,            &Bl[(w * 32) * 32]);
    gld_lds16(gb + 16 * DD,  &Bl[(w * 32 + 16) * 32]);
    __syncthreads();

    bf16x8 af[4], bfv[4];
#pragma unroll
    for (int t = 0; t < 4; ++t) {
      af[t]  = *(const bf16x8*)&Al[(wr + t * 16 + l15) * 32 + l4 * 8];
      bfv[t] = *(const bf16x8*)&Bl[(wc + t * 16 + l15) * 32 + l4 * 8];
    }
#pragma unroll
    for (int mt = 0; mt < 4; ++mt)
#pragma unroll
      for (int nt = 0; nt < 4; ++nt)
        acc[mt][nt] = mfma16(af[mt], bfv[nt], acc[mt][nt]);
    __syncthreads();
  }

#pragma unroll
  for (int mt = 0; mt < 4; ++mt)
#pragma unroll
    for (int nt = 0; nt < 4; ++nt)
#pragma unroll
      for (int r = 0; r < 4; ++r) {
        const size_t row = m0 + wr + mt * 16 + l4 * 4 + r;
        const size_t col = n0 + wc + nt * 16 + l15;
        C[row * DD + col] = acc[mt][nt][r];
      }
}

// --- flash attention v17: QBLK=32 zero-LDS main loop, K+V fragment streams -
__global__ __launch_bounds__(256)
void k_attn(const bf16* __restrict__ Qw, const bf16* __restrict__ Kf,
            const bf16* __restrict__ Vf, const unsigned* __restrict__ mb,
            bf16* __restrict__ Xw) {
  __shared__ struct { float o[64 * 33]; float l[4][32]; float inv[32]; } sh;
  const int tid = threadIdx.x, lane = tid & 63, w = tid >> 6;
  const int l31 = lane & 31, hi = lane >> 5;
  const unsigned bid = blockIdx.x;
  const unsigned wg = (bid & 7) * 256 + (bid >> 3);   // XCD swizzle (2048 = 8*256)
  const int bh = wg >> 5, qblk = wg & 31;
  const int h = bh & 15, b = bh >> 4;
  const int q0 = qblk * 32;

  // Q fragments (B operand): Q[q0 + l31][kt*16 + hi*8 + j]
  bf16x8 qf[4];
  {
    const bf16* Qb = Qw + (size_t)(b * SS + q0 + l31) * DD + h * 64 + hi * 8;
#pragma unroll
    for (int kt = 0; kt < 4; ++kt) qf[kt] = *(const bf16x8*)(Qb + kt * 16);
  }
  const bf16* Kfb = Kf + ((size_t)((b * HH + h) * 32 + w * 8)) * 2048 + lane * 8;
  const bf16* Vfb = Vf + ((size_t)((b * HH + h) * 32 + w * 8)) * 2048 + lane * 8;
  const unsigned* mq = mb +
      ((size_t)((((b * 16 + (qblk >> 1)) * 2 + (qblk & 1)) * 4 + w) * 8)) * 32 + l31;

  f32x16 aco[2];
#pragma unroll
  for (int dt = 0; dt < 2; ++dt)
#pragma unroll
    for (int r = 0; r < 16; ++r) aco[dt][r] = 0.f;
  float ssum = 0.f;

  for (int t = 0; t < 8; ++t) {
    const bf16* tk = Kfb + t * 2048;
    bf16x8 kf[4];
#pragma unroll
    for (int kt = 0; kt < 4; ++kt) kf[kt] = *(const bf16x8*)(tk + kt * 512);
    const unsigned mw = mq[t * 32];

    // swapped QK^T: S[kv][q=l31]
    f32x16 s;
#pragma unroll
    for (int r = 0; r < 16; ++r) s[r] = 0.f;
    __builtin_amdgcn_s_setprio(1);
#pragma unroll
    for (int kt = 0; kt < 4; ++kt) s = mfma32(kf[kt], qf[kt], s);
    __builtin_amdgcn_s_setprio(0);

    // V fragments: coalesced stream loads, covered by softmax+pack below
    bf16x8 va[2][2];
    {
      const bf16* tv = Vfb + t * 2048;
#pragma unroll
      for (int s2 = 0; s2 < 2; ++s2)
#pragma unroll
        for (int dt = 0; dt < 2; ++dt)
          va[dt][s2] = *(const bf16x8*)(tv + (s2 * 2 + dt) * 512);
    }

    // fixed-reference softmax: p = exp2(masked s); masked -> 0
    float p[16];
#pragma unroll
    for (int r = 0; r < 16; ++r) {
      const int pos = (r & 3) + 8 * (r >> 2) + 4 * hi;
      p[r] = fexp2(((mw >> pos) & 1) ? s[r] : -1e9f);
    }
    {
      float a0 = (p[0] + p[1]) + (p[2] + p[3]);
      float a1 = (p[4] + p[5]) + (p[6] + p[7]);
      float a2 = (p[8] + p[9]) + (p[10] + p[11]);
      float a3 = (p[12] + p[13]) + (p[14] + p[15]);
      ssum += (a0 + a1) + (a2 + a3);
    }
    // pack + XOR-32 routing (verified r7/r9/r10/r12)
    int dpk[8];
#pragma unroll
    for (int i = 0; i < 8; ++i) {
      union { bf16 hh[2]; int v; } u;
      u.hh[0] = (bf16)p[2 * i]; u.hh[1] = (bf16)p[2 * i + 1];
      dpk[i] = u.v;
    }
    const int sa = hi ? dpk[0] : dpk[2], sb = hi ? dpk[1] : dpk[3];
    const int sc_ = hi ? dpk[4] : dpk[6], sd = hi ? dpk[5] : dpk[7];
    const int ra = __shfl_xor(sa, 32), rb = __shfl_xor(sb, 32);
    const int rc = __shfl_xor(sc_, 32), rd = __shfl_xor(sd, 32);
    union { bf16x8 v; int q[4]; } pa0, pa1;
    pa0.q[0] = hi ? ra : dpk[0];  pa0.q[1] = hi ? rb : dpk[1];
    pa0.q[2] = hi ? dpk[2] : ra;  pa0.q[3] = hi ? dpk[3] : rb;
    pa1.q[0] = hi ? rc : dpk[4];  pa1.q[1] = hi ? rd : dpk[5];
    pa1.q[2] = hi ? dpk[6] : rc;  pa1.q[3] = hi ? dpk[7] : rd;

    // PV (O^T): aco[dt] += V^T * P^T
    __builtin_amdgcn_s_setprio(1);
#pragma unroll
    for (int dt = 0; dt < 2; ++dt) {
      aco[dt] = mfma32(va[dt][0], pa0.v, aco[dt]);
      aco[dt] = mfma32(va[dt][1], pa1.v, aco[dt]);
    }
    __builtin_amdgcn_s_setprio(0);
  }

  // ---- merge 4 kv-quarter partials: plain sums ----
  ssum += __shfl_xor(ssum, 32);
  __syncthreads();
  if (hi == 0) sh.l[w][l31] = ssum;
  __syncthreads();
  if (tid < 32) {
    sh.inv[tid] = 1.0f / (sh.l[0][tid] + sh.l[1][tid] +
                          sh.l[2][tid] + sh.l[3][tid]);
  }
  __syncthreads();
  for (int rd2 = 0; rd2 < 4; ++rd2) {
    if (w == rd2) {
#pragma unroll
      for (int dt = 0; dt < 2; ++dt)
#pragma unroll
        for (int r = 0; r < 16; ++r) {
          const int d = dt * 32 + (r & 3) + 8 * (r >> 2) + 4 * hi;
          const int o = d * 33 + l31;
          if (rd2 == 0) sh.o[o] = aco[dt][r];
          else          sh.o[o] += aco[dt][r];
        }
    }
    __syncthreads();
  }
  {
    const int q = tid >> 3, d0 = (tid & 7) * 8;     // o is [d][q] (stride 33)
    const float inv = sh.inv[q];
    bf16x8 ov;
#pragma unroll
    for (int j = 0; j < 8; ++j) ov[j] = (bf16)(sh.o[(d0 + j) * 33 + q] * inv);
    *(bf16x8*)(Xw + (size_t)(b * SS + q0 + q) * DD + h * 64 + d0) = ov;
  }
}

// ---------------- launch ----------------
extern "C" void kernel_launch(void* const* d_in, const int* in_sizes, int n_in,
                              void* d_out, int out_size, void* d_ws, size_t ws_size,
                              hipStream_t stream) {
  const float* q32 = (const float*)d_in[0];
  const float* k32 = (const float*)d_in[1];
  const float* v32 = (const float*)d_in[2];
  const int* mask = (const int*)d_in[3];
  const float* Wq = (const float*)d_in[4];
  const float* Wk = (const float*)d_in[5];
  const float* Wv = (const float*)d_in[6];
  const float* Wo = (const float*)d_in[7];
  float* out = (float*)d_out;

  const size_t eAct = (size_t)MM * DD;
  const size_t eW = (size_t)DD * DD;

  bf16* Qb = (bf16*)d_ws;
  bf16* Kb = Qb + eAct;          // row-major K (k_frag input)
  bf16* Vb = Kb + eAct;          // row-major V (k_frag input)
  bf16* Xb = Vb + eAct;
  unsigned* mbits = (unsigned*)(Xb + eAct);
  bf16* Kfp = (bf16*)(mbits + (size_t)MM * 32);
  bf16* Vfp = Kfp + eAct;
  bf16* cvtBase = Vfp + eAct;
  bf16* Aq = cvtBase;
  bf16* Ak = Aq + eAct;
  bf16* Av = Ak + eAct;
  bf16* Wqb = Av + eAct;
  bf16* Wkb = Wqb + eW;
  bf16* Wvb = Wkb + eW;
  bf16* Wob = Wvb + eW;
  const size_t need = (size_t)((bf16*)(Wob + eW) - (bf16*)d_ws) * sizeof(bf16);

  if (ws_size >= need) {
    k_prep<<<dim3(2048, 8), 256, 0, stream>>>(q32, k32, v32, Wq, Wk, Wv, Wo,
                                              Aq, Ak, Av, Wqb, Wkb, Wvb, Wob,
                                              mask, mbits);
    k_gemm_qkv_b16<<<dim3(256, 1, 3), 256, 0, stream>>>(
        Aq, Ak, Av, Wqb, Wkb, Wvb, Qb, Kb, Vb);
    k_frag<<<dim3(32, HH, BB), 256, 0, stream>>>(Kb, Vb, Kfp, Vfp);
    k_attn<<<BB * HH * (SS / 32), 256, 0, stream>>>(Qb, Kfp, Vfp, mbits, Xb);
    k_gemm_out_b16<<<256, 256, 0, stream>>>(Xb, Wob, out);
  } else {
    k_mask_bits<<<BB * SS, 256, 0, stream>>>(mask, mbits);
    k_gemm_qkv<<<dim3((MM / 128) * (DD / 128), 1, 3), 256, 0, stream>>>(
        q32, k32, v32, Wq, Wk, Wv, Qb, Kb, Vb);
    k_frag<<<dim3(32, HH, BB), 256, 0, stream>>>(Kb, Vb, Kfp, Vfp);
    k_attn<<<BB * HH * (SS / 32), 256, 0, stream>>>(Qb, Kfp, Vfp, mbits, Xb);
    k_gemm_out<<<(MM / 128) * (DD / 128), 256, 0, stream>>>(Xb, Wo, out);
  }
}

// Round 20
// 119.839 us; speedup vs baseline: 1.0329x; 1.0329x over previous
//
#include <hip/hip_runtime.h>

#define BB 4
#define SS 1024
#define DD 1024
#define HH 16
#define DKK 64
#define MM (BB*SS)   // 4096

typedef __bf16 bf16;
typedef __bf16 bf16x8 __attribute__((ext_vector_type(8)));
typedef float f32x4 __attribute__((ext_vector_type(4)));
typedef float f32x16 __attribute__((ext_vector_type(16)));

__device__ __forceinline__ f32x4 mfma16(bf16x8 a, bf16x8 b, f32x4 c) {
  return __builtin_amdgcn_mfma_f32_16x16x32_bf16(a, b, c, 0, 0, 0);
}
__device__ __forceinline__ f32x16 mfma32(bf16x8 a, bf16x8 b, f32x16 c) {
  return __builtin_amdgcn_mfma_f32_32x32x16_bf16(a, b, c, 0, 0, 0);
}
__device__ __forceinline__ float fexp2(float x) {
  return __builtin_amdgcn_exp2f(x);
}
__device__ __forceinline__ void gld_lds16(const bf16* g, bf16* l) {
  __builtin_amdgcn_global_load_lds(
      (const __attribute__((address_space(1))) void*)g,
      (__attribute__((address_space(3))) void*)l, 16, 0, 0);
}

// ------- prep: fp32->bf16 convert (7 tensors) + mask bits, one dispatch ----
__global__ __launch_bounds__(256)
void k_prep(const float* __restrict__ s0, const float* __restrict__ s1,
            const float* __restrict__ s2, const float* __restrict__ s3,
            const float* __restrict__ s4, const float* __restrict__ s5,
            const float* __restrict__ s6,
            bf16* __restrict__ d0, bf16* __restrict__ d1, bf16* __restrict__ d2,
            bf16* __restrict__ d3, bf16* __restrict__ d4, bf16* __restrict__ d5,
            bf16* __restrict__ d6,
            const int* __restrict__ mask, unsigned* __restrict__ bits) {
  const int t = blockIdx.y;
  if (t < 7) {
    const float* s = (t == 0) ? s0 : (t == 1) ? s1 : (t == 2) ? s2
                   : (t == 3) ? s3 : (t == 4) ? s4 : (t == 5) ? s5 : s6;
    bf16* d = (t == 0) ? d0 : (t == 1) ? d1 : (t == 2) ? d2
            : (t == 3) ? d3 : (t == 4) ? d4 : (t == 5) ? d5 : d6;
    const int n = (t < 3) ? (MM * DD) : (DD * DD);
    const int i0 = (blockIdx.x * 256 + threadIdx.x) * 8;
    if (i0 >= n) return;
    const f32x4 a = *(const f32x4*)(s + i0);
    const f32x4 bvv = *(const f32x4*)(s + i0 + 4);
    bf16x8 o;
#pragma unroll
    for (int j = 0; j < 4; ++j) { o[j] = (bf16)a[j]; o[4 + j] = (bf16)bvv[j]; }
    *(bf16x8*)(d + i0) = o;
    return;
  }
  const int tid = threadIdx.x;
  const int lane = tid & 63, wv = tid >> 6;
#pragma unroll
  for (int rr = 0; rr < 2; ++rr) {
    const int row = blockIdx.x * 2 + rr;           // b*S + q
    const int b = row >> 10, q = row & 1023;
    const int qblk = q >> 6, qt = (q >> 5) & 1, l = q & 31;
    const size_t base = ((size_t)(b * 16 + qblk) * 2 + qt) * 4;
#pragma unroll
    for (int it = 0; it < 4; ++it) {
      const int cb = it * 256 + wv * 64;
      unsigned long long bal = __ballot(mask[(size_t)row * SS + cb + lane] != 0);
      if (lane == 0) {
        const int c0 = cb >> 5;
#pragma unroll
        for (int dd = 0; dd < 2; ++dd) {
          const int c = c0 + dd;
          bits[((base + (c >> 3)) * 8 + (c & 7)) * 32 + l] =
              (unsigned)(bal >> (32 * dd));
        }
      }
    }
  }
}

// ---------------- mask -> bitmask (standalone, fallback path) --------------
__global__ __launch_bounds__(256) void k_mask_bits(const int* __restrict__ mask,
                                                   unsigned* __restrict__ bits) {
  const int row = blockIdx.x;
  const int b = row >> 10, q = row & 1023;
  const int qblk = q >> 6, qt = (q >> 5) & 1, l = q & 31;
  const size_t base = ((size_t)(b * 16 + qblk) * 2 + qt) * 4;
  const int tid = threadIdx.x;
  const int lane = tid & 63, wv = tid >> 6;
#pragma unroll
  for (int it = 0; it < 4; ++it) {
    const int cb = it * 256 + wv * 64;
    unsigned long long bal = __ballot(mask[(size_t)row * SS + cb + lane] != 0);
    if (lane == 0) {
      const int c0 = cb >> 5;
#pragma unroll
      for (int dd = 0; dd < 2; ++dd) {
        const int c = c0 + dd;
        bits[((base + (c >> 3)) * 8 + (c & 7)) * 32 + l] =
            (unsigned)(bal >> (32 * dd));
      }
    }
  }
}

// ------- K/V -> MFMA fragment order (r11-verified layout) ------------------
__global__ __launch_bounds__(256)
void k_frag(const bf16* __restrict__ K, const bf16* __restrict__ V,
            bf16* __restrict__ Kf, bf16* __restrict__ Vf) {
  __shared__ bf16 Kl[32 * 66];
  __shared__ bf16 Vl[32 * 66];
  const int kvb = blockIdx.x, h = blockIdx.y, b = blockIdx.z;
  const int tid = threadIdx.x;
  const int r = tid >> 3, c0 = (tid & 7) * 8;
  const size_t src = (size_t)(b * SS + kvb * 32 + r) * DD + h * 64 + c0;
  *(bf16x8*)&Kl[r * 66 + c0] = *(const bf16x8*)(K + src);
  *(bf16x8*)&Vl[r * 66 + c0] = *(const bf16x8*)(V + src);
  __syncthreads();
  const int lane = tid & 63, l31 = lane & 31, hi = lane >> 5;
  const size_t tb = ((size_t)((b * HH + h) * 32 + kvb)) * 2048 + tid * 8;
  {
    const int kt = tid >> 6;
    bf16x8 ok;
#pragma unroll
    for (int j = 0; j < 8; ++j) ok[j] = Kl[l31 * 66 + kt * 16 + hi * 8 + j];
    *(bf16x8*)(Kf + tb) = ok;
  }
  {
    const int s2 = tid >> 7, dt = (tid >> 6) & 1;
    bf16x8 ov;
#pragma unroll
    for (int j = 0; j < 8; ++j)
      ov[j] = Vl[(s2 * 16 + hi * 8 + j) * 66 + dt * 32 + l31];
    *(bf16x8*)(Vf + tb) = ov;
  }
}

// Q pre-scaled by 1/sqrt(dk) * log2(e): attention runs in exp2 domain.
#define QSCALE 0.1803368801111204f

// ---------------- legacy GEMM (fallback when ws too small) ----------------
template<int AF32, int CF32>
__device__ __forceinline__ void gemm_body(const void* __restrict__ Ap,
                                          const float* __restrict__ Wp,
                                          void* __restrict__ Cp,
                                          int Mtot, int N, int K, int blk,
                                          float oscale) {
  __shared__ bf16 Al[128 * 40];
  __shared__ bf16 Bl[128 * 40];
  const int tid = threadIdx.x;
  const int lane = tid & 63;
  const int l15 = lane & 15, l4 = lane >> 4;
  const int wv = tid >> 6;
  const int nbm = Mtot >> 7;
  const int bm = blk % nbm, bn = blk / nbm;
  const size_t m0 = (size_t)bm << 7, n0 = (size_t)bn << 7;
  const int wr = (wv >> 1) << 6, wc = (wv & 1) << 6;
  const int srow = tid >> 2, scol = (tid & 3) << 3;

  f32x4 acc[4][4];
#pragma unroll
  for (int i = 0; i < 4; ++i)
#pragma unroll
    for (int j = 0; j < 4; ++j) acc[i][j] = f32x4{0.f, 0.f, 0.f, 0.f};

  for (int k0 = 0; k0 < K; k0 += 32) {
#pragma unroll
    for (int c = 0; c < 2; ++c) {
      const int row = (c << 6) + srow;
      bf16x8 av;
      if (AF32) {
        const float* s = (const float*)Ap + (m0 + row) * (size_t)K + k0 + scol;
        f32x4 v0 = *(const f32x4*)s;
        f32x4 v1 = *(const f32x4*)(s + 4);
#pragma unroll
        for (int j = 0; j < 4; ++j) { av[j] = (bf16)v0[j]; av[4 + j] = (bf16)v1[j]; }
      } else {
        av = *(const bf16x8*)((const bf16*)Ap + (m0 + row) * (size_t)K + k0 + scol);
      }
      *(bf16x8*)&Al[row * 40 + scol] = av;

      const float* ws_ = Wp + (n0 + row) * (size_t)K + k0 + scol;
      f32x4 w0 = *(const f32x4*)ws_;
      f32x4 w1 = *(const f32x4*)(ws_ + 4);
      bf16x8 wv8;
#pragma unroll
      for (int j = 0; j < 4; ++j) { wv8[j] = (bf16)w0[j]; wv8[4 + j] = (bf16)w1[j]; }
      *(bf16x8*)&Bl[row * 40 + scol] = wv8;
    }
    __syncthreads();

    bf16x8 af[4], bfv[4];
#pragma unroll
    for (int t = 0; t < 4; ++t) {
      af[t]  = *(const bf16x8*)&Al[(wr + t * 16 + l15) * 40 + l4 * 8];
      bfv[t] = *(const bf16x8*)&Bl[(wc + t * 16 + l15) * 40 + l4 * 8];
    }
    __builtin_amdgcn_s_setprio(1);
#pragma unroll
    for (int mt = 0; mt < 4; ++mt)
#pragma unroll
      for (int nt = 0; nt < 4; ++nt)
        acc[mt][nt] = mfma16(af[mt], bfv[nt], acc[mt][nt]);
    __builtin_amdgcn_s_setprio(0);
    __syncthreads();
  }

#pragma unroll
  for (int mt = 0; mt < 4; ++mt)
#pragma unroll
    for (int nt = 0; nt < 4; ++nt)
#pragma unroll
      for (int r = 0; r < 4; ++r) {
        const size_t row = m0 + wr + mt * 16 + l4 * 4 + r;
        const size_t col = n0 + wc + nt * 16 + l15;
        if (CF32) ((float*)Cp)[row * N + col] = acc[mt][nt][r];
        else      ((bf16*)Cp)[row * N + col] = (bf16)(acc[mt][nt][r] * oscale);
      }
}

__global__ __launch_bounds__(256)
void k_gemm_qkv(const float* __restrict__ A0, const float* __restrict__ A1,
                const float* __restrict__ A2, const float* __restrict__ W0,
                const float* __restrict__ W1, const float* __restrict__ W2,
                bf16* __restrict__ C0, bf16* __restrict__ C1, bf16* __restrict__ C2) {
  const int z = blockIdx.z;
  const float* A = (z == 0) ? A0 : (z == 1) ? A1 : A2;
  const float* W = (z == 0) ? W0 : (z == 1) ? W1 : W2;
  bf16* C = (z == 0) ? C0 : (z == 1) ? C1 : C2;
  const float sc = (z == 0) ? QSCALE : 1.0f;
  gemm_body<1, 0>(A, W, C, MM, DD, DD, blockIdx.x, sc);
}

__global__ __launch_bounds__(256)
void k_gemm_out(const bf16* __restrict__ A, const float* __restrict__ W,
                float* __restrict__ C) {
  gemm_body<0, 1>(A, W, C, MM, DD, DD, blockIdx.x, 1.0f);
}

// ---------------- bf16 GEMM with global_load_lds (m97 structure) ----------
__global__ __launch_bounds__(256)
void k_gemm_qkv_b16(const bf16* __restrict__ A0, const bf16* __restrict__ A1,
                    const bf16* __restrict__ A2, const bf16* __restrict__ W0,
                    const bf16* __restrict__ W1, const bf16* __restrict__ W2,
                    bf16* __restrict__ C0, bf16* __restrict__ C1,
                    bf16* __restrict__ C2) {
  __shared__ bf16 Al[128 * 32];
  __shared__ bf16 Bl[128 * 32];
  const int z = blockIdx.z;
  const bf16* A = (z == 0) ? A0 : (z == 1) ? A1 : A2;
  const bf16* W = (z == 0) ? W0 : (z == 1) ? W1 : W2;
  bf16* C = (z == 0) ? C0 : (z == 1) ? C1 : C2;
  const float oscale = (z == 0) ? QSCALE : 1.0f;

  const int tid = threadIdx.x, lane = tid & 63, w = tid >> 6;
  const int l15 = lane & 15, l4 = lane >> 4;
  const int bm = blockIdx.x & 31, bn = blockIdx.x >> 5;
  const size_t m0 = (size_t)bm << 7, n0 = (size_t)bn << 7;
  const int wr = (w >> 1) << 6, wc = (w & 1) << 6;
  const int srow = w * 32 + (lane >> 2);
  const int scol = (lane & 3) << 3;

  f32x4 acc[4][4];
#pragma unroll
  for (int i = 0; i < 4; ++i)
#pragma unroll
    for (int j = 0; j < 4; ++j) acc[i][j] = f32x4{0.f, 0.f, 0.f, 0.f};

  for (int k0 = 0; k0 < DD; k0 += 32) {
    const bf16* ga = A + (m0 + srow) * (size_t)DD + k0 + scol;
    const bf16* gb = W + (n0 + srow) * (size_t)DD + k0 + scol;
    gld_lds16(ga,            &Al[(w * 32) * 32]);
    gld_lds16(ga + 16 * DD,  &Al[(w * 32 + 16) * 32]);
    gld_lds16(gb,            &Bl[(w * 32) * 32]);
    gld_lds16(gb + 16 * DD,  &Bl[(w * 32 + 16) * 32]);
    __syncthreads();

    bf16x8 af[4], bfv[4];
#pragma unroll
    for (int t = 0; t < 4; ++t) {
      af[t]  = *(const bf16x8*)&Al[(wr + t * 16 + l15) * 32 + l4 * 8];
      bfv[t] = *(const bf16x8*)&Bl[(wc + t * 16 + l15) * 32 + l4 * 8];
    }
#pragma unroll
    for (int mt = 0; mt < 4; ++mt)
#pragma unroll
      for (int nt = 0; nt < 4; ++nt)
        acc[mt][nt] = mfma16(af[mt], bfv[nt], acc[mt][nt]);
    __syncthreads();
  }

#pragma unroll
  for (int mt = 0; mt < 4; ++mt)
#pragma unroll
    for (int nt = 0; nt < 4; ++nt)
#pragma unroll
      for (int r = 0; r < 4; ++r) {
        const size_t row = m0 + wr + mt * 16 + l4 * 4 + r;
        const size_t col = n0 + wc + nt * 16 + l15;
        C[row * DD + col] = (bf16)(acc[mt][nt][r] * oscale);
      }
}

// --- out GEMM: 64x128 tile (grid 512 = 2 blocks/CU for latency overlap) ----
__global__ __launch_bounds__(256)
void k_gemm_out_b16(const bf16* __restrict__ A, const bf16* __restrict__ W,
                    float* __restrict__ C) {
  __shared__ bf16 Al[64 * 32];    // 4 KiB
  __shared__ bf16 Bl[128 * 32];   // 8 KiB
  const int tid = threadIdx.x, lane = tid & 63, w = tid >> 6;
  const int l15 = lane & 15, l4 = lane >> 4;
  const int bm = blockIdx.x & 63, bn = blockIdx.x >> 6;
  const size_t m0 = (size_t)bm << 6, n0 = (size_t)bn << 7;
  const int wr = (w >> 1) << 5, wc = (w & 1) << 6;   // wave: 32 rows x 64 cols
  const int srA = w * 16 + (lane >> 2);              // A: 16 rows/wave
  const int srB = w * 32 + (lane >> 2);              // B: 32 rows/wave
  const int scol = (lane & 3) << 3;

  f32x4 acc[2][4];
#pragma unroll
  for (int i = 0; i < 2; ++i)
#pragma unroll
    for (int j = 0; j < 4; ++j) acc[i][j] = f32x4{0.f, 0.f, 0.f, 0.f};

  for (int k0 = 0; k0 < DD; k0 += 32) {
    const bf16* ga = A + (m0 + srA) * (size_t)DD + k0 + scol;
    const bf16* gb = W + (n0 + srB) * (size_t)DD + k0 + scol;
    gld_lds16(ga,           &Al[(w * 16) * 32]);
    gld_lds16(gb,           &Bl[(w * 32) * 32]);
    gld_lds16(gb + 16 * DD, &Bl[(w * 32 + 16) * 32]);
    __syncthreads();

    bf16x8 af[2], bfv[4];
#pragma unroll
    for (int t = 0; t < 2; ++t)
      af[t] = *(const bf16x8*)&Al[(wr + t * 16 + l15) * 32 + l4 * 8];
#pragma unroll
    for (int t = 0; t < 4; ++t)
      bfv[t] = *(const bf16x8*)&Bl[(wc + t * 16 + l15) * 32 + l4 * 8];
#pragma unroll
    for (int mt = 0; mt < 2; ++mt)
#pragma unroll
      for (int nt = 0; nt < 4; ++nt)
        acc[mt][nt] = mfma16(af[mt], bfv[nt], acc[mt][nt]);
    __syncthreads();
  }

#pragma unroll
  for (int mt = 0; mt < 2; ++mt)
#pragma unroll
    for (int nt = 0; nt < 4; ++nt)
#pragma unroll
      for (int r = 0; r < 4; ++r) {
        const size_t row = m0 + wr + mt * 16 + l4 * 4 + r;
        const size_t col = n0 + wc + nt * 16 + l15;
        C[row * DD + col] = acc[mt][nt][r];
      }
}

// --- flash attention v17: QBLK=32 zero-LDS main loop, K+V fragment streams -
__global__ __launch_bounds__(256)
void k_attn(const bf16* __restrict__ Qw, const bf16* __restrict__ Kf,
            const bf16* __restrict__ Vf, const unsigned* __restrict__ mb,
            bf16* __restrict__ Xw) {
  __shared__ struct { float o[64 * 33]; float l[4][32]; float inv[32]; } sh;
  const int tid = threadIdx.x, lane = tid & 63, w = tid >> 6;
  const int l31 = lane & 31, hi = lane >> 5;
  const unsigned bid = blockIdx.x;
  const unsigned wg = (bid & 7) * 256 + (bid >> 3);   // XCD swizzle (2048 = 8*256)
  const int bh = wg >> 5, qblk = wg & 31;
  const int h = bh & 15, b = bh >> 4;
  const int q0 = qblk * 32;

  // Q fragments (B operand): Q[q0 + l31][kt*16 + hi*8 + j]
  bf16x8 qf[4];
  {
    const bf16* Qb = Qw + (size_t)(b * SS + q0 + l31) * DD + h * 64 + hi * 8;
#pragma unroll
    for (int kt = 0; kt < 4; ++kt) qf[kt] = *(const bf16x8*)(Qb + kt * 16);
  }
  const bf16* Kfb = Kf + ((size_t)((b * HH + h) * 32 + w * 8)) * 2048 + lane * 8;
  const bf16* Vfb = Vf + ((size_t)((b * HH + h) * 32 + w * 8)) * 2048 + lane * 8;
  const unsigned* mq = mb +
      ((size_t)((((b * 16 + (qblk >> 1)) * 2 + (qblk & 1)) * 4 + w) * 8)) * 32 + l31;

  f32x16 aco[2];
#pragma unroll
  for (int dt = 0; dt < 2; ++dt)
#pragma unroll
    for (int r = 0; r < 16; ++r) aco[dt][r] = 0.f;
  float ssum = 0.f;

  for (int t = 0; t < 8; ++t) {
    const bf16* tk = Kfb + t * 2048;
    bf16x8 kf[4];
#pragma unroll
    for (int kt = 0; kt < 4; ++kt) kf[kt] = *(const bf16x8*)(tk + kt * 512);
    const unsigned mw = mq[t * 32];

    // swapped QK^T: S[kv][q=l31]
    f32x16 s;
#pragma unroll
    for (int r = 0; r < 16; ++r) s[r] = 0.f;
    __builtin_amdgcn_s_setprio(1);
#pragma unroll
    for (int kt = 0; kt < 4; ++kt) s = mfma32(kf[kt], qf[kt], s);
    __builtin_amdgcn_s_setprio(0);

    // V fragments: coalesced stream loads, covered by softmax+pack below
    bf16x8 va[2][2];
    {
      const bf16* tv = Vfb + t * 2048;
#pragma unroll
      for (int s2 = 0; s2 < 2; ++s2)
#pragma unroll
        for (int dt = 0; dt < 2; ++dt)
          va[dt][s2] = *(const bf16x8*)(tv + (s2 * 2 + dt) * 512);
    }

    // fixed-reference softmax: p = exp2(masked s); masked -> 0
    float p[16];
#pragma unroll
    for (int r = 0; r < 16; ++r) {
      const int pos = (r & 3) + 8 * (r >> 2) + 4 * hi;
      p[r] = fexp2(((mw >> pos) & 1) ? s[r] : -1e9f);
    }
    {
      float a0 = (p[0] + p[1]) + (p[2] + p[3]);
      float a1 = (p[4] + p[5]) + (p[6] + p[7]);
      float a2 = (p[8] + p[9]) + (p[10] + p[11]);
      float a3 = (p[12] + p[13]) + (p[14] + p[15]);
      ssum += (a0 + a1) + (a2 + a3);
    }
    // pack + XOR-32 routing (verified r7/r9/r10/r12)
    int dpk[8];
#pragma unroll
    for (int i = 0; i < 8; ++i) {
      union { bf16 hh[2]; int v; } u;
      u.hh[0] = (bf16)p[2 * i]; u.hh[1] = (bf16)p[2 * i + 1];
      dpk[i] = u.v;
    }
    const int sa = hi ? dpk[0] : dpk[2], sb = hi ? dpk[1] : dpk[3];
    const int sc_ = hi ? dpk[4] : dpk[6], sd = hi ? dpk[5] : dpk[7];
    const int ra = __shfl_xor(sa, 32), rb = __shfl_xor(sb, 32);
    const int rc = __shfl_xor(sc_, 32), rd = __shfl_xor(sd, 32);
    union { bf16x8 v; int q[4]; } pa0, pa1;
    pa0.q[0] = hi ? ra : dpk[0];  pa0.q[1] = hi ? rb : dpk[1];
    pa0.q[2] = hi ? dpk[2] : ra;  pa0.q[3] = hi ? dpk[3] : rb;
    pa1.q[0] = hi ? rc : dpk[4];  pa1.q[1] = hi ? rd : dpk[5];
    pa1.q[2] = hi ? dpk[6] : rc;  pa1.q[3] = hi ? dpk[7] : rd;

    // PV (O^T): aco[dt] += V^T * P^T
    __builtin_amdgcn_s_setprio(1);
#pragma unroll
    for (int dt = 0; dt < 2; ++dt) {
      aco[dt] = mfma32(va[dt][0], pa0.v, aco[dt]);
      aco[dt] = mfma32(va[dt][1], pa1.v, aco[dt]);
    }
    __builtin_amdgcn_s_setprio(0);
  }

  // ---- merge 4 kv-quarter partials: plain sums ----
  ssum += __shfl_xor(ssum, 32);
  __syncthreads();
  if (hi == 0) sh.l[w][l31] = ssum;
  __syncthreads();
  if (tid < 32) {
    sh.inv[tid] = 1.0f / (sh.l[0][tid] + sh.l[1][tid] +
                          sh.l[2][tid] + sh.l[3][tid]);
  }
  __syncthreads();
  for (int rd2 = 0; rd2 < 4; ++rd2) {
    if (w == rd2) {
#pragma unroll
      for (int dt = 0; dt < 2; ++dt)
#pragma unroll
        for (int r = 0; r < 16; ++r) {
          const int d = dt * 32 + (r & 3) + 8 * (r >> 2) + 4 * hi;
          const int o = d * 33 + l31;
          if (rd2 == 0) sh.o[o] = aco[dt][r];
          else          sh.o[o] += aco[dt][r];
        }
    }
    __syncthreads();
  }
  {
    const int q = tid >> 3, d0 = (tid & 7) * 8;     // o is [d][q] (stride 33)
    const float inv = sh.inv[q];
    bf16x8 ov;
#pragma unroll
    for (int j = 0; j < 8; ++j) ov[j] = (bf16)(sh.o[(d0 + j) * 33 + q] * inv);
    *(bf16x8*)(Xw + (size_t)(b * SS + q0 + q) * DD + h * 64 + d0) = ov;
  }
}

// ---------------- launch ----------------
extern "C" void kernel_launch(void* const* d_in, const int* in_sizes, int n_in,
                              void* d_out, int out_size, void* d_ws, size_t ws_size,
                              hipStream_t stream) {
  const float* q32 = (const float*)d_in[0];
  const float* k32 = (const float*)d_in[1];
  const float* v32 = (const float*)d_in[2];
  const int* mask = (const int*)d_in[3];
  const float* Wq = (const float*)d_in[4];
  const float* Wk = (const float*)d_in[5];
  const float* Wv = (const float*)d_in[6];
  const float* Wo = (const float*)d_in[7];
  float* out = (float*)d_out;

  const size_t eAct = (size_t)MM * DD;
  const size_t eW = (size_t)DD * DD;

  bf16* Qb = (bf16*)d_ws;
  bf16* Kb = Qb + eAct;          // row-major K (k_frag input)
  bf16* Vb = Kb + eAct;          // row-major V (k_frag input)
  bf16* Xb = Vb + eAct;
  unsigned* mbits = (unsigned*)(Xb + eAct);
  bf16* Kfp = (bf16*)(mbits + (size_t)MM * 32);
  bf16* Vfp = Kfp + eAct;
  bf16* cvtBase = Vfp + eAct;
  bf16* Aq = cvtBase;
  bf16* Ak = Aq + eAct;
  bf16* Av = Ak + eAct;
  bf16* Wqb = Av + eAct;
  bf16* Wkb = Wqb + eW;
  bf16* Wvb = Wkb + eW;
  bf16* Wob = Wvb + eW;
  const size_t need = (size_t)((bf16*)(Wob + eW) - (bf16*)d_ws) * sizeof(bf16);

  if (ws_size >= need) {
    k_prep<<<dim3(2048, 8), 256, 0, stream>>>(q32, k32, v32, Wq, Wk, Wv, Wo,
                                              Aq, Ak, Av, Wqb, Wkb, Wvb, Wob,
                                              mask, mbits);
    k_gemm_qkv_b16<<<dim3(256, 1, 3), 256, 0, stream>>>(
        Aq, Ak, Av, Wqb, Wkb, Wvb, Qb, Kb, Vb);
    k_frag<<<dim3(32, HH, BB), 256, 0, stream>>>(Kb, Vb, Kfp, Vfp);
    k_attn<<<BB * HH * (SS / 32), 256, 0, stream>>>(Qb, Kfp, Vfp, mbits, Xb);
    k_gemm_out_b16<<<512, 256, 0, stream>>>(Xb, Wob, out);
  } else {
    k_mask_bits<<<BB * SS, 256, 0, stream>>>(mask, mbits);
    k_gemm_qkv<<<dim3((MM / 128) * (DD / 128), 1, 3), 256, 0, stream>>>(
        q32, k32, v32, Wq, Wk, Wv, Qb, Kb, Vb);
    k_frag<<<dim3(32, HH, BB), 256, 0, stream>>>(Kb, Vb, Kfp, Vfp);
    k_attn<<<BB * HH * (SS / 32), 256, 0, stream>>>(Qb, Kfp, Vfp, mbits, Xb);
    k_gemm_out<<<(MM / 128) * (DD / 128), 256, 0, stream>>>(Xb, Wo, out);
  }
}